// Round 9
// baseline (10207.660 us; speedup 1.0000x reference)
//
#include <hip/hip_runtime.h>

// LSTM: B=1024, T=128, I=128, H=1024, O=64
// R10: PERSISTENT cooperative kernel. R4/R7/R9 all land 15-17us/step across
//      different schedules -> invariant per-step fixed costs (launch gap,
//      first-tile stall, c reload, full-device kernel-boundary sync) cap
//      every structure. Fuse 128 steps into one hipLaunchCooperativeKernel:
//      - 8 independent per-mb atomic barriers (32 blocks each; h is only
//        coupled within an mb group) instead of device-wide boundaries
//      - c state persists in registers (replaces cold[2][4], 0 extra VGPR)
//      - next step's K-tiles 0,1 are pure-xb -> staged DURING the spin
//      - inner 18-tile loop is R7's verified asm-ds_read/counted-vmcnt
//        pipeline verbatim; raw s_barrier after spin keeps the ledger.

#define B_DIM 1024
#define H_DIM 1024
#define I_DIM 128
#define T_DIM 128
#define XROW  (T_DIM * I_DIM)   // 16384
#define KDIM  (I_DIM + H_DIM)   // 1152
#define GDIM  (4 * H_DIM)       // 4096
#define O_DIM 64

typedef float f32x4 __attribute__((ext_vector_type(4)));
typedef short bf16x8 __attribute__((ext_vector_type(8)));
typedef unsigned short u16x8 __attribute__((ext_vector_type(8)));

__device__ __forceinline__ unsigned short f2bf(float f) {
    union { float f; unsigned int u; } v; v.f = f;
    unsigned int r = v.u + 0x7fffu + ((v.u >> 16) & 1u);  // RNE
    return (unsigned short)(r >> 16);
}
__device__ __forceinline__ float bf2f(unsigned short b) {
    union { unsigned int u; float f; } v; v.u = ((unsigned int)b) << 16;
    return v.f;
}
__device__ __forceinline__ float sigm(float x) { return 1.f / (1.f + __expf(-x)); }
__device__ __forceinline__ float tanh_fast(float x) { return 2.f / (1.f + __expf(-2.f * x)) - 1.f; }

// ---- prep: fp32 x -> bf16 ----
__global__ void conv_x(const float* __restrict__ x, unsigned short* __restrict__ xb) {
    size_t i = ((size_t)blockIdx.x * 256 + threadIdx.x) * 8;
    float4 v0 = *(const float4*)(x + i);
    float4 v1 = *(const float4*)(x + i + 4);
    u16x8 o;
    o[0] = f2bf(v0.x); o[1] = f2bf(v0.y); o[2] = f2bf(v0.z); o[3] = f2bf(v0.w);
    o[4] = f2bf(v1.x); o[5] = f2bf(v1.y); o[6] = f2bf(v1.z); o[7] = f2bf(v1.w);
    *(u16x8*)(xb + i) = o;
}

// ---- prep: gate-interleaved W'' [4096 x 1152] bf16 + combined bias ----
__global__ void build_w(const float* __restrict__ w_ih, const float* __restrict__ w_hh,
                        const float* __restrict__ b_ih, const float* __restrict__ b_hh,
                        unsigned short* __restrict__ W, float* __restrict__ bias) {
    int r = blockIdx.x;
    int nb = r >> 7, q = r & 127;
    int wh = q >> 6, w = q & 63;
    int gate = w >> 4, jl = w & 15;
    int orig = gate * 1024 + nb * 32 + wh * 16 + jl;
    for (int k = threadIdx.x; k < KDIM; k += 256) {
        float v = (k < I_DIM) ? w_ih[(size_t)orig * I_DIM + k]
                              : w_hh[(size_t)orig * H_DIM + (k - I_DIM)];
        W[(size_t)r * KDIM + k] = f2bf(v);
    }
    if (threadIdx.x == 0) bias[r] = b_ih[orig] + b_hh[orig];
}

// ---- prep: transpose w_fc [O][H] -> wT [H][O] so proj loads coalesce ----
__global__ void trans_wfc(const float* __restrict__ w_fc, float* __restrict__ wT) {
    int o = blockIdx.x;
    for (int k = threadIdx.x; k < H_DIM; k += 256)
        wT[(size_t)k * O_DIM + o] = w_fc[(size_t)o * H_DIM + k];
}

// zero h0 + the 8 padded sync counters (runs each graph replay)
__global__ void zero_h(unsigned short* __restrict__ h0, unsigned int* __restrict__ sync) {
    int idx = blockIdx.x * 256 + threadIdx.x;
    h0[idx] = 0;
    if (blockIdx.x == 0 && threadIdx.x < 128) sync[threadIdx.x] = 0;
}

// 12 ds_read_b128 for one K-tile. OFF selects buffer (0 / 32768 bytes).
// kk=32 fragments are addr^64 (== swizzled col (x^4)<<4 for x<8).
#define READ_TILE(OFF) do {                                                       \
    asm volatile("ds_read_b128 %0, %1 offset:" OFF : "=v"(fa0) : "v"(aA0));       \
    asm volatile("ds_read_b128 %0, %1 offset:" OFF : "=v"(fa1) : "v"(aA1));       \
    asm volatile("ds_read_b128 %0, %1 offset:" OFF : "=v"(fb0) : "v"(aB0));       \
    asm volatile("ds_read_b128 %0, %1 offset:" OFF : "=v"(fb1) : "v"(aB1));       \
    asm volatile("ds_read_b128 %0, %1 offset:" OFF : "=v"(fb2) : "v"(aB2));       \
    asm volatile("ds_read_b128 %0, %1 offset:" OFF : "=v"(fb3) : "v"(aB3));       \
    asm volatile("ds_read_b128 %0, %1 offset:" OFF : "=v"(ga0) : "v"(aA0x));      \
    asm volatile("ds_read_b128 %0, %1 offset:" OFF : "=v"(ga1) : "v"(aA1x));      \
    asm volatile("ds_read_b128 %0, %1 offset:" OFF : "=v"(gb0) : "v"(aB0x));      \
    asm volatile("ds_read_b128 %0, %1 offset:" OFF : "=v"(gb1) : "v"(aB1x));      \
    asm volatile("ds_read_b128 %0, %1 offset:" OFF : "=v"(gb2) : "v"(aB2x));      \
    asm volatile("ds_read_b128 %0, %1 offset:" OFF : "=v"(gb3) : "v"(aB3x));      \
    asm volatile("s_waitcnt lgkmcnt(0)" ::: "memory");                            \
    __builtin_amdgcn_sched_barrier(0);                                            \
} while (0)

#define MFMA_(a, b, c) c = __builtin_amdgcn_mfma_f32_16x16x32_bf16(a, b, c, 0, 0, 0)
#define MM_TILE() do {                                                            \
    MFMA_(fa0, fb0, acc[0][0]); MFMA_(fa0, fb1, acc[0][1]);                       \
    MFMA_(fa0, fb2, acc[0][2]); MFMA_(fa0, fb3, acc[0][3]);                       \
    MFMA_(fa1, fb0, acc[1][0]); MFMA_(fa1, fb1, acc[1][1]);                       \
    MFMA_(fa1, fb2, acc[1][2]); MFMA_(fa1, fb3, acc[1][3]);                       \
    MFMA_(ga0, gb0, acc[0][0]); MFMA_(ga0, gb1, acc[0][1]);                       \
    MFMA_(ga0, gb2, acc[0][2]); MFMA_(ga0, gb3, acc[0][3]);                       \
    MFMA_(ga1, gb0, acc[1][0]); MFMA_(ga1, gb1, acc[1][1]);                       \
    MFMA_(ga1, gb2, acc[1][2]); MFMA_(ga1, gb3, acc[1][3]);                       \
} while (0)

// ---- persistent kernel: all 128 timesteps, per-mb-group barriers ----
__global__ __launch_bounds__(512, 2)
void lstm_all(const unsigned short* __restrict__ xb,
              const unsigned short* __restrict__ W,
              const float* __restrict__ bias,
              unsigned short* __restrict__ h0,
              unsigned short* __restrict__ h1,
              unsigned int* __restrict__ sync) {
    // buffers: buf0 A@0 B@16384, buf1 A@32768 B@49152 (bytes)
    __shared__ __align__(16) unsigned short lds[4 * 8192];
    const int tid  = threadIdx.x;
    const int wv   = tid >> 6, lane = tid & 63;
    const int wm   = wv >> 1, wn = wv & 1;      // 4x2 wave grid over 128x128
    const int quad = lane >> 4, l16 = lane & 15;
    const int l7   = l16 & 7;
    const int bid = blockIdx.x;
    const int xcd = bid & 7;
    const int sl  = bid >> 3;            // 0..31
    const int nb  = xcd * 4 + (sl & 3);  // 0..31 : XCD x owns nb in [4x,4x+4)
    const int mb  = sl >> 2;             // 0..7  : sync group

    const int j  = nb * 32 + wn * 16 + l16;
    const int bb = nb * 128 + wn * 64 + l16;
    const float bi  = bias[bb +  0];
    const float bf_ = bias[bb + 16];
    const float bg  = bias[bb + 32];
    const float bo  = bias[bb + 48];
    float creg[2][4];                    // persistent cell state (all 128 steps)
#pragma unroll
    for (int mi = 0; mi < 2; mi++)
#pragma unroll
        for (int r = 0; r < 4; r++) creg[mi][r] = 0.f;

    const int arow = lane >> 3;
    const int ag   = lane & 7;
    const int colperm = ((ag ^ arow) << 3);

    unsigned short* hin  = h0;
    unsigned short* hout = h1;

    // stage one 64-wide K-tile into buffer bsel for step tt: 4 DMA loads/wave
    auto stage = [&](int bsel, int ks, int tt) {
        const int kt = ks * 64;
        unsigned short* As_ = lds + bsel * 16384;
        unsigned short* Bs_ = As_ + 8192;
#pragma unroll
        for (int c4 = 0; c4 < 2; ++c4) {
            const int row0 = wv * 16 + c4 * 8;
            const int row  = row0 + arow;
            const unsigned short* srcA =
                (kt < I_DIM)
                    ? xb  + (size_t)(mb * 128 + row) * XROW + tt * I_DIM + kt + colperm
                    : hin + (size_t)(mb * 128 + row) * H_DIM + (kt - I_DIM) + colperm;
            __builtin_amdgcn_global_load_lds(
                (const __attribute__((address_space(1))) void*)srcA,
                (__attribute__((address_space(3))) void*)(&As_[row0 * 64]), 16, 0, 0);
        }
#pragma unroll
        for (int c4 = 0; c4 < 2; ++c4) {
            const int row0 = wv * 16 + c4 * 8;
            const int row  = row0 + arow;
            const unsigned short* srcB =
                W + (size_t)(nb * 128 + row) * KDIM + kt + colperm;
            __builtin_amdgcn_global_load_lds(
                (const __attribute__((address_space(1))) void*)srcB,
                (__attribute__((address_space(3))) void*)(&Bs_[row0 * 64]), 16, 0, 0);
        }
    };

    // asm ds_read addresses (bytes): row stride 128, frag col = (quad^l7)<<4
    const unsigned lbase = (unsigned)(unsigned long long)
        (__attribute__((address_space(3))) void*)lds;
    const unsigned cp  = (unsigned)((quad ^ l7) << 4);
    const unsigned aA0 = lbase + (unsigned)((wm * 32 + l16) * 128) + cp;
    const unsigned aA1 = aA0 + 2048;
    const unsigned aB0 = lbase + 16384u + (unsigned)((wn * 64 + l16) * 128) + cp;
    const unsigned aB1 = aB0 + 2048;
    const unsigned aB2 = aB0 + 4096;
    const unsigned aB3 = aB0 + 6144;
    const unsigned aA0x = aA0 ^ 64u, aA1x = aA1 ^ 64u;
    const unsigned aB0x = aB0 ^ 64u, aB1x = aB1 ^ 64u;
    const unsigned aB2x = aB2 ^ 64u, aB3x = aB3 ^ 64u;
    bf16x8 fa0, fa1, fb0, fb1, fb2, fb3, ga0, ga1, gb0, gb1, gb2, gb3;

    unsigned int* cnt = sync + mb * 16;  // 64B-padded counter per mb group

    // prologue for t=0 (tiles 0,1 are pure-xb)
    stage(0, 0, 0);
    stage(1, 1, 0);

#pragma unroll 1
    for (int t = 0; t < T_DIM; ++t) {
        f32x4 acc[2][4];
#pragma unroll
        for (int i = 0; i < 2; i++)
#pragma unroll
            for (int jj = 0; jj < 4; jj++) acc[i][jj] = f32x4{0.f, 0.f, 0.f, 0.f};

        // ---- R7's counted-vmcnt pipeline: tiles 0..17 ----
#pragma unroll 1
        for (int p = 0; p < 8; ++p) {
            asm volatile("s_waitcnt vmcnt(4)" ::: "memory");
            __builtin_amdgcn_s_barrier();
            READ_TILE("0");
            __builtin_amdgcn_s_barrier();
            stage(0, 2 * p + 2, t);
            MM_TILE();

            asm volatile("s_waitcnt vmcnt(4)" ::: "memory");
            __builtin_amdgcn_s_barrier();
            READ_TILE("32768");
            __builtin_amdgcn_s_barrier();
            stage(1, 2 * p + 3, t);
            MM_TILE();
        }
        asm volatile("s_waitcnt vmcnt(4)" ::: "memory");
        __builtin_amdgcn_s_barrier();
        READ_TILE("0");                              // tile 16
        MM_TILE();
        asm volatile("s_waitcnt vmcnt(0)" ::: "memory");
        __builtin_amdgcn_s_barrier();
        READ_TILE("32768");                          // tile 17
        MM_TILE();

        // ---- epilogue: gates -> c (regs) -> h_out store ----
#pragma unroll
        for (int mi = 0; mi < 2; mi++) {
#pragma unroll
            for (int r = 0; r < 4; r++) {
                const int brow = mb * 128 + wm * 32 + mi * 16 + quad * 4 + r;
                const float gi = acc[mi][0][r] + bi;
                const float gf = acc[mi][1][r] + bf_;
                const float gg = acc[mi][2][r] + bg;
                const float go = acc[mi][3][r] + bo;
                const float cn = sigm(gf) * creg[mi][r] + sigm(gi) * tanh_fast(gg);
                creg[mi][r] = cn;
                hout[(size_t)brow * H_DIM + j] = f2bf(sigm(go) * tanh_fast(cn));
            }
        }

        if (t < T_DIM - 1) {
            // publish h_out: drain+fence each wave, block-sync, release-arrive
            __threadfence();
            __syncthreads();
            if (tid == 0)
                __hip_atomic_fetch_add(cnt, 1u, __ATOMIC_RELEASE,
                                       __HIP_MEMORY_SCOPE_AGENT);
            // stage next step's xb-only tiles under the spin
            stage(0, 0, t + 1);
            stage(1, 1, t + 1);
            if (tid == 0) {
                const unsigned tgt = 32u * (unsigned)(t + 1);
                while (__hip_atomic_load(cnt, __ATOMIC_RELAXED,
                                         __HIP_MEMORY_SCOPE_AGENT) < tgt) {}
                (void)__hip_atomic_load(cnt, __ATOMIC_ACQUIRE,
                                        __HIP_MEMORY_SCOPE_AGENT);
            }
            __builtin_amdgcn_s_barrier();   // raw: keeps 8 loads in flight
            unsigned short* tmp = hin; hin = hout; hout = tmp;
        }
    }
}

// ---- final projection: 4 batch rows per block, lane = output dim ----
__global__ void proj(const unsigned short* __restrict__ h,
                     const float* __restrict__ wT,
                     const float* __restrict__ b_fc,
                     float* __restrict__ out) {
    __shared__ float hs[4][H_DIM];
    const int tid = threadIdx.x, wv = tid >> 6, o = tid & 63;
    const int b = blockIdx.x * 4 + wv;
    const unsigned short* hrow = h + (size_t)b * H_DIM;
#pragma unroll
    for (int i = 0; i < 2; ++i) {
        const int k0 = i * 512 + o * 8;
        u16x8 v = *(const u16x8*)(hrow + k0);
        float4 f0 = {bf2f((unsigned short)v[0]), bf2f((unsigned short)v[1]),
                     bf2f((unsigned short)v[2]), bf2f((unsigned short)v[3])};
        float4 f1 = {bf2f((unsigned short)v[4]), bf2f((unsigned short)v[5]),
                     bf2f((unsigned short)v[6]), bf2f((unsigned short)v[7])};
        *(float4*)&hs[wv][k0]     = f0;
        *(float4*)&hs[wv][k0 + 4] = f1;
    }
    float s0 = 0.f, s1 = 0.f, s2 = 0.f, s3 = 0.f;
#pragma unroll 4
    for (int k4 = 0; k4 < H_DIM / 4; ++k4) {
        float4 hv = *(const float4*)&hs[wv][k4 * 4];
        const float* wp = wT + (size_t)k4 * 4 * O_DIM + o;
        s0 += hv.x * wp[0 * O_DIM];
        s1 += hv.y * wp[1 * O_DIM];
        s2 += hv.z * wp[2 * O_DIM];
        s3 += hv.w * wp[3 * O_DIM];
    }
    out[(size_t)b * O_DIM + o] = s0 + s1 + s2 + s3 + b_fc[o];
}

extern "C" void kernel_launch(void* const* d_in, const int* in_sizes, int n_in,
                              void* d_out, int out_size, void* d_ws, size_t ws_size,
                              hipStream_t stream) {
    const float* x    = (const float*)d_in[0];
    const float* w_ih = (const float*)d_in[1];
    const float* w_hh = (const float*)d_in[2];
    const float* b_ih = (const float*)d_in[3];
    const float* b_hh = (const float*)d_in[4];
    const float* w_fc = (const float*)d_in[5];
    const float* b_fc = (const float*)d_in[6];
    float* out = (float*)d_out;

    char* ws = (char*)d_ws;
    size_t off = 0;
    unsigned short* xb = (unsigned short*)(ws + off); off += (size_t)B_DIM * XROW * 2;
    unsigned short* W  = (unsigned short*)(ws + off); off += (size_t)GDIM * KDIM * 2;
    float* bias        = (float*)(ws + off);          off += (size_t)GDIM * 4;
    unsigned short* h0 = (unsigned short*)(ws + off); off += (size_t)B_DIM * H_DIM * 2;
    unsigned short* h1 = (unsigned short*)(ws + off); off += (size_t)B_DIM * H_DIM * 2;
    unsigned int* sync = (unsigned int*)(ws + off);   off += 128 * 4;
    float* wT          = (float*)(ws + off);          off += (size_t)H_DIM * O_DIM * 4;

    conv_x<<<8192, 256, 0, stream>>>(x, xb);
    build_w<<<GDIM, 256, 0, stream>>>(w_ih, w_hh, b_ih, b_hh, W, bias);
    trans_wfc<<<O_DIM, 256, 0, stream>>>(w_fc, wT);
    zero_h<<<4096, 256, 0, stream>>>(h0, sync);

    void* params[] = {(void*)&xb, (void*)&W, (void*)&bias,
                      (void*)&h0, (void*)&h1, (void*)&sync};
    hipLaunchCooperativeKernel((const void*)lstm_all, dim3(256), dim3(512),
                               params, 0, stream);

    // t=127 wrote h0 (odd t -> hout == h0)
    proj<<<256, 256, 0, stream>>>(h0, wT, b_fc, out);
}

// Round 10
// 1816.362 us; speedup vs baseline: 5.6198x; 5.6198x over previous
//
#include <hip/hip_runtime.h>

// LSTM: B=1024, T=128, I=128, H=1024, O=64
// R11: REVERT R10 (persistent kernel: per-step agent-scope fences =
//      full L2 wbinv per step -> 5x regression, MfmaUtil 4.8%). Base = R7.
//      CHANGE: 4-buffer round-robin K-loop pipeline:
//        - ONE s_barrier per tile (was 2): stage(k+3) targets buf (k-1)%4,
//          whose reads all waves finished before this phase's barrier
//          (lgkm0 precedes each wave's MFMA/arrival).
//        - 2 tiles in flight steady (vmcnt(8), was vmcnt(4)/1-deep) ->
//          double the L2-latency cover on staging.
//      Ledger: prologue tiles 0,1,2; phases 0..15 vmcnt(8); 16 vmcnt(4);
//      17 vmcnt(0). Bufs 2,3 via +65536 addr set (DS offset is 16-bit).
//      Everything else identical to R7 (1976us verified).

#define B_DIM 1024
#define H_DIM 1024
#define I_DIM 128
#define T_DIM 128
#define XROW  (T_DIM * I_DIM)   // 16384
#define KDIM  (I_DIM + H_DIM)   // 1152
#define GDIM  (4 * H_DIM)       // 4096
#define O_DIM 64

typedef float f32x4 __attribute__((ext_vector_type(4)));
typedef short bf16x8 __attribute__((ext_vector_type(8)));
typedef unsigned short u16x8 __attribute__((ext_vector_type(8)));

__device__ __forceinline__ unsigned short f2bf(float f) {
    union { float f; unsigned int u; } v; v.f = f;
    unsigned int r = v.u + 0x7fffu + ((v.u >> 16) & 1u);  // RNE
    return (unsigned short)(r >> 16);
}
__device__ __forceinline__ float bf2f(unsigned short b) {
    union { unsigned int u; float f; } v; v.u = ((unsigned int)b) << 16;
    return v.f;
}
__device__ __forceinline__ float sigm(float x) { return 1.f / (1.f + __expf(-x)); }
__device__ __forceinline__ float tanh_fast(float x) { return 2.f / (1.f + __expf(-2.f * x)) - 1.f; }

// ---- prep: fp32 x -> bf16 ----
__global__ void conv_x(const float* __restrict__ x, unsigned short* __restrict__ xb) {
    size_t i = ((size_t)blockIdx.x * 256 + threadIdx.x) * 8;
    float4 v0 = *(const float4*)(x + i);
    float4 v1 = *(const float4*)(x + i + 4);
    u16x8 o;
    o[0] = f2bf(v0.x); o[1] = f2bf(v0.y); o[2] = f2bf(v0.z); o[3] = f2bf(v0.w);
    o[4] = f2bf(v1.x); o[5] = f2bf(v1.y); o[6] = f2bf(v1.z); o[7] = f2bf(v1.w);
    *(u16x8*)(xb + i) = o;
}

// ---- prep: gate-interleaved W'' [4096 x 1152] bf16 + combined bias ----
__global__ void build_w(const float* __restrict__ w_ih, const float* __restrict__ w_hh,
                        const float* __restrict__ b_ih, const float* __restrict__ b_hh,
                        unsigned short* __restrict__ W, float* __restrict__ bias) {
    int r = blockIdx.x;
    int nb = r >> 7, q = r & 127;
    int wh = q >> 6, w = q & 63;
    int gate = w >> 4, jl = w & 15;
    int orig = gate * 1024 + nb * 32 + wh * 16 + jl;
    for (int k = threadIdx.x; k < KDIM; k += 256) {
        float v = (k < I_DIM) ? w_ih[(size_t)orig * I_DIM + k]
                              : w_hh[(size_t)orig * H_DIM + (k - I_DIM)];
        W[(size_t)r * KDIM + k] = f2bf(v);
    }
    if (threadIdx.x == 0) bias[r] = b_ih[orig] + b_hh[orig];
}

// ---- prep: transpose w_fc [O][H] -> wT [H][O] so proj loads coalesce ----
__global__ void trans_wfc(const float* __restrict__ w_fc, float* __restrict__ wT) {
    int o = blockIdx.x;
    for (int k = threadIdx.x; k < H_DIM; k += 256)
        wT[(size_t)k * O_DIM + o] = w_fc[(size_t)o * H_DIM + k];
}

__global__ void zero_hc(unsigned short* __restrict__ h0, float* __restrict__ c) {
    int idx = blockIdx.x * 256 + threadIdx.x;
    h0[idx] = 0;
    c[idx] = 0.f;
}

// 12 ds_read_b128 for one K-tile from address set (A0,A1,B0..B3) at OFF.
// kk=32 fragments via addr^64 (== swizzled col (x^4)<<4 for x<8).
#define READ_TILE(A0, A1, B0, B1, B2, B3, OFF) do {                               \
    asm volatile("ds_read_b128 %0, %1 offset:" OFF : "=v"(fa0) : "v"(A0));        \
    asm volatile("ds_read_b128 %0, %1 offset:" OFF : "=v"(fa1) : "v"(A1));        \
    asm volatile("ds_read_b128 %0, %1 offset:" OFF : "=v"(fb0) : "v"(B0));        \
    asm volatile("ds_read_b128 %0, %1 offset:" OFF : "=v"(fb1) : "v"(B1));        \
    asm volatile("ds_read_b128 %0, %1 offset:" OFF : "=v"(fb2) : "v"(B2));        \
    asm volatile("ds_read_b128 %0, %1 offset:" OFF : "=v"(fb3) : "v"(B3));        \
    asm volatile("ds_read_b128 %0, %1 offset:" OFF : "=v"(ga0) : "v"((A0) ^ 64u));\
    asm volatile("ds_read_b128 %0, %1 offset:" OFF : "=v"(ga1) : "v"((A1) ^ 64u));\
    asm volatile("ds_read_b128 %0, %1 offset:" OFF : "=v"(gb0) : "v"((B0) ^ 64u));\
    asm volatile("ds_read_b128 %0, %1 offset:" OFF : "=v"(gb1) : "v"((B1) ^ 64u));\
    asm volatile("ds_read_b128 %0, %1 offset:" OFF : "=v"(gb2) : "v"((B2) ^ 64u));\
    asm volatile("ds_read_b128 %0, %1 offset:" OFF : "=v"(gb3) : "v"((B3) ^ 64u));\
    asm volatile("s_waitcnt lgkmcnt(0)" ::: "memory");                            \
    __builtin_amdgcn_sched_barrier(0);                                            \
} while (0)

#define MFMA_(a, b, c) c = __builtin_amdgcn_mfma_f32_16x16x32_bf16(a, b, c, 0, 0, 0)
#define MM_TILE() do {                                                            \
    MFMA_(fa0, fb0, acc[0][0]); MFMA_(fa0, fb1, acc[0][1]);                       \
    MFMA_(fa0, fb2, acc[0][2]); MFMA_(fa0, fb3, acc[0][3]);                       \
    MFMA_(fa1, fb0, acc[1][0]); MFMA_(fa1, fb1, acc[1][1]);                       \
    MFMA_(fa1, fb2, acc[1][2]); MFMA_(fa1, fb3, acc[1][3]);                       \
    MFMA_(ga0, gb0, acc[0][0]); MFMA_(ga0, gb1, acc[0][1]);                       \
    MFMA_(ga0, gb2, acc[0][2]); MFMA_(ga0, gb3, acc[0][3]);                       \
    MFMA_(ga1, gb0, acc[1][0]); MFMA_(ga1, gb1, acc[1][1]);                       \
    MFMA_(ga1, gb2, acc[1][2]); MFMA_(ga1, gb3, acc[1][3]);                       \
} while (0)

#define WAITV(N) do {                                                             \
    asm volatile("s_waitcnt vmcnt(" N ")" ::: "memory");                          \
    __builtin_amdgcn_s_barrier();                                                 \
} while (0)

// ---- per-timestep: 128x128 tile GEMM + fused LSTM cell epilogue ----
__global__ __launch_bounds__(512, 2)
void lstm_step(const unsigned short* __restrict__ xb,
               const unsigned short* __restrict__ W,
               const float* __restrict__ bias,
               const unsigned short* __restrict__ h_in,
               unsigned short* __restrict__ h_out,
               float* __restrict__ c_st,
               int t) {
    // 4 buffers x 32KB: buf k at byte 32768*k; within: A@0, B@16384
    __shared__ __align__(16) unsigned short lds[8 * 8192];
    const int tid  = threadIdx.x;
    const int wv   = tid >> 6, lane = tid & 63;
    const int wm   = wv >> 1, wn = wv & 1;      // 4x2 wave grid over 128x128
    const int quad = lane >> 4, l16 = lane & 15;
    const int l7   = l16 & 7;
    const int bid = blockIdx.x;
    const int xcd = bid & 7;
    const int sl  = bid >> 3;            // 0..31
    const int nb  = xcd * 4 + (sl & 3);  // 0..31 : XCD x owns nb in [4x,4x+4)
    const int mb  = sl >> 2;             // 0..7

    // epilogue addressing + prefetch of bias and old cell state
    const int j  = nb * 32 + wn * 16 + l16;
    const int bb = nb * 128 + wn * 64 + l16;
    const float bi  = bias[bb +  0];
    const float bf_ = bias[bb + 16];
    const float bg  = bias[bb + 32];
    const float bo  = bias[bb + 48];
    float cold[2][4];
#pragma unroll
    for (int mi = 0; mi < 2; mi++)
#pragma unroll
        for (int r = 0; r < 4; r++) {
            const int brow = mb * 128 + wm * 32 + mi * 16 + quad * 4 + r;
            cold[mi][r] = c_st[(size_t)brow * H_DIM + j];
        }

    f32x4 acc[2][4];
#pragma unroll
    for (int i = 0; i < 2; i++)
#pragma unroll
        for (int jj = 0; jj < 4; jj++) acc[i][jj] = f32x4{0.f, 0.f, 0.f, 0.f};

    const int arow = lane >> 3;              // 0..7: row within 8-row chunk
    const int ag   = lane & 7;               // physical 16B group this lane fills
    const int colperm = ((ag ^ arow) << 3);  // swizzled source column (bf16 units)

    // stage one 64-wide K-tile into buffer bsel (0..3): 4 DMA loads/wave
    auto stage = [&](int bsel, int ks) {
        const int kt = ks * 64;
        unsigned short* As_ = lds + bsel * 16384;
        unsigned short* Bs_ = As_ + 8192;
#pragma unroll
        for (int c4 = 0; c4 < 2; ++c4) {
            const int row0 = wv * 16 + c4 * 8;
            const int row  = row0 + arow;
            const unsigned short* srcA =
                (kt < I_DIM)
                    ? xb   + (size_t)(mb * 128 + row) * XROW + t * I_DIM + kt + colperm
                    : h_in + (size_t)(mb * 128 + row) * H_DIM + (kt - I_DIM) + colperm;
            __builtin_amdgcn_global_load_lds(
                (const __attribute__((address_space(1))) void*)srcA,
                (__attribute__((address_space(3))) void*)(&As_[row0 * 64]), 16, 0, 0);
        }
#pragma unroll
        for (int c4 = 0; c4 < 2; ++c4) {
            const int row0 = wv * 16 + c4 * 8;
            const int row  = row0 + arow;
            const unsigned short* srcB =
                W + (size_t)(nb * 128 + row) * KDIM + kt + colperm;
            __builtin_amdgcn_global_load_lds(
                (const __attribute__((address_space(1))) void*)srcB,
                (__attribute__((address_space(3))) void*)(&Bs_[row0 * 64]), 16, 0, 0);
        }
    };

    // address set 0 (bufs 0/1 via offset 0/32768); set 1 = +65536 (bufs 2/3)
    const unsigned lbase = (unsigned)(unsigned long long)
        (__attribute__((address_space(3))) void*)lds;
    const unsigned cp  = (unsigned)((quad ^ l7) << 4);
    const unsigned aA0 = lbase + (unsigned)((wm * 32 + l16) * 128) + cp;
    const unsigned aA1 = aA0 + 2048;
    const unsigned aB0 = lbase + 16384u + (unsigned)((wn * 64 + l16) * 128) + cp;
    const unsigned aB1 = aB0 + 2048;
    const unsigned aB2 = aB0 + 4096;
    const unsigned aB3 = aB0 + 6144;
    const unsigned cA0 = aA0 + 65536u, cA1 = aA1 + 65536u;
    const unsigned cB0 = aB0 + 65536u, cB1 = aB1 + 65536u;
    const unsigned cB2 = aB2 + 65536u, cB3 = aB3 + 65536u;
    bf16x8 fa0, fa1, fb0, fb1, fb2, fb3, ga0, ga1, gb0, gb1, gb2, gb3;

    // ---- prologue: tiles 0,1,2 (12 outstanding) ----
    stage(0, 0);
    stage(1, 1);
    stage(2, 2);

    // phases 0..11: uniform, stage tile k+3 into buf (k+3)%4
#pragma unroll 1
    for (int q = 0; q < 3; ++q) {
        WAITV("8"); READ_TILE(aA0, aA1, aB0, aB1, aB2, aB3, "0");
        stage(3, 4 * q + 3); MM_TILE();
        WAITV("8"); READ_TILE(aA0, aA1, aB0, aB1, aB2, aB3, "32768");
        stage(0, 4 * q + 4); MM_TILE();
        WAITV("8"); READ_TILE(cA0, cA1, cB0, cB1, cB2, cB3, "0");
        stage(1, 4 * q + 5); MM_TILE();
        WAITV("8"); READ_TILE(cA0, cA1, cB0, cB1, cB2, cB3, "32768");
        stage(2, 4 * q + 6); MM_TILE();
    }
    // phases 12..17 (stages for tiles 15,16,17; then drain)
    WAITV("8"); READ_TILE(aA0, aA1, aB0, aB1, aB2, aB3, "0");      // tile 12
    stage(3, 15); MM_TILE();
    WAITV("8"); READ_TILE(aA0, aA1, aB0, aB1, aB2, aB3, "32768");  // tile 13
    stage(0, 16); MM_TILE();
    WAITV("8"); READ_TILE(cA0, cA1, cB0, cB1, cB2, cB3, "0");      // tile 14
    stage(1, 17); MM_TILE();
    WAITV("8"); READ_TILE(cA0, cA1, cB0, cB1, cB2, cB3, "32768");  // tile 15
    MM_TILE();
    WAITV("4"); READ_TILE(aA0, aA1, aB0, aB1, aB2, aB3, "0");      // tile 16
    MM_TILE();
    WAITV("0"); READ_TILE(aA0, aA1, aB0, aB1, aB2, aB3, "32768");  // tile 17
    MM_TILE();

    // epilogue: ni == gate (0:i 1:f 2:g 3:o), fully in-lane
#pragma unroll
    for (int mi = 0; mi < 2; mi++) {
#pragma unroll
        for (int r = 0; r < 4; r++) {
            const int brow = mb * 128 + wm * 32 + mi * 16 + quad * 4 + r;
            const float gi = acc[mi][0][r] + bi;
            const float gf = acc[mi][1][r] + bf_;
            const float gg = acc[mi][2][r] + bg;
            const float go = acc[mi][3][r] + bo;
            const size_t idx = (size_t)brow * H_DIM + j;
            const float cn = sigm(gf) * cold[mi][r] + sigm(gi) * tanh_fast(gg);
            c_st[idx] = cn;
            h_out[idx] = f2bf(sigm(go) * tanh_fast(cn));
        }
    }
}

// ---- final projection: 4 batch rows per block, lane = output dim ----
__global__ void proj(const unsigned short* __restrict__ h,
                     const float* __restrict__ wT,
                     const float* __restrict__ b_fc,
                     float* __restrict__ out) {
    __shared__ float hs[4][H_DIM];
    const int tid = threadIdx.x, wv = tid >> 6, o = tid & 63;
    const int b = blockIdx.x * 4 + wv;
    const unsigned short* hrow = h + (size_t)b * H_DIM;
#pragma unroll
    for (int i = 0; i < 2; ++i) {
        const int k0 = i * 512 + o * 8;
        u16x8 v = *(const u16x8*)(hrow + k0);
        float4 f0 = {bf2f((unsigned short)v[0]), bf2f((unsigned short)v[1]),
                     bf2f((unsigned short)v[2]), bf2f((unsigned short)v[3])};
        float4 f1 = {bf2f((unsigned short)v[4]), bf2f((unsigned short)v[5]),
                     bf2f((unsigned short)v[6]), bf2f((unsigned short)v[7])};
        *(float4*)&hs[wv][k0]     = f0;
        *(float4*)&hs[wv][k0 + 4] = f1;
    }
    float s0 = 0.f, s1 = 0.f, s2 = 0.f, s3 = 0.f;
#pragma unroll 4
    for (int k4 = 0; k4 < H_DIM / 4; ++k4) {
        float4 hv = *(const float4*)&hs[wv][k4 * 4];
        const float* wp = wT + (size_t)k4 * 4 * O_DIM + o;
        s0 += hv.x * wp[0 * O_DIM];
        s1 += hv.y * wp[1 * O_DIM];
        s2 += hv.z * wp[2 * O_DIM];
        s3 += hv.w * wp[3 * O_DIM];
    }
    out[(size_t)b * O_DIM + o] = s0 + s1 + s2 + s3 + b_fc[o];
}

extern "C" void kernel_launch(void* const* d_in, const int* in_sizes, int n_in,
                              void* d_out, int out_size, void* d_ws, size_t ws_size,
                              hipStream_t stream) {
    const float* x    = (const float*)d_in[0];
    const float* w_ih = (const float*)d_in[1];
    const float* w_hh = (const float*)d_in[2];
    const float* b_ih = (const float*)d_in[3];
    const float* b_hh = (const float*)d_in[4];
    const float* w_fc = (const float*)d_in[5];
    const float* b_fc = (const float*)d_in[6];
    float* out = (float*)d_out;

    char* ws = (char*)d_ws;
    size_t off = 0;
    unsigned short* xb = (unsigned short*)(ws + off); off += (size_t)B_DIM * XROW * 2;
    unsigned short* W  = (unsigned short*)(ws + off); off += (size_t)GDIM * KDIM * 2;
    float* bias        = (float*)(ws + off);          off += (size_t)GDIM * 4;
    unsigned short* h0 = (unsigned short*)(ws + off); off += (size_t)B_DIM * H_DIM * 2;
    unsigned short* h1 = (unsigned short*)(ws + off); off += (size_t)B_DIM * H_DIM * 2;
    float* c           = (float*)(ws + off);          off += (size_t)B_DIM * H_DIM * 4;
    float* wT          = (float*)(ws + off);          off += (size_t)H_DIM * O_DIM * 4;

    conv_x<<<8192, 256, 0, stream>>>(x, xb);
    build_w<<<GDIM, 256, 0, stream>>>(w_ih, w_hh, b_ih, b_hh, W, bias);
    trans_wfc<<<O_DIM, 256, 0, stream>>>(w_fc, wT);
    zero_hc<<<4096, 256, 0, stream>>>(h0, c);

    for (int t = 0; t < T_DIM; ++t) {
        const unsigned short* hin = (t & 1) ? h1 : h0;
        unsigned short* hout      = (t & 1) ? h0 : h1;
        lstm_step<<<256, 512, 0, stream>>>(xb, W, bias, hin, hout, c, t);
    }
    // t=127 wrote h0
    proj<<<256, 256, 0, stream>>>(h0, wT, b_fc, out);
}